// Round 1
// 561.652 us; speedup vs baseline: 1.0731x; 1.0731x over previous
//
#include <hip/hip_runtime.h>
#include <math.h>

#define HIDDEN 2048
#define NHEAD 16
#define HD 128
#define SEQ 2048
#define BATCH 2
#define MROWS (BATCH * SEQ)   // 4096
#define K3 (3 * HIDDEN)       // 6144

#define SCORE_SCALE 0.08838834764831845f  // 1/sqrt(128), LAYER_NUMBER=1

using short8 = __attribute__((ext_vector_type(8))) short;
using f32x4 = __attribute__((ext_vector_type(4))) float;

__device__ __forceinline__ unsigned short f2bf(float f) {
  union { float f; unsigned int u; } v; v.f = f;
  const unsigned int u = v.u;
  return (unsigned short)((u + 0x7FFFu + ((u >> 16) & 1u)) >> 16);
}

// async 16B global -> LDS (global addr per-lane; LDS dest uniform base + lane*16)
__device__ __forceinline__ void gl2lds16(const void* g, void* l) {
#pragma clang diagnostic push
#pragma clang diagnostic ignored "-Waddress-space-conversion"
  __builtin_amdgcn_global_load_lds(
      (const __attribute__((address_space(1))) unsigned int*)g,
      (__attribute__((address_space(3))) unsigned int*)l, 16, 0, 0);
#pragma clang diagnostic pop
}

// ---------------------------------------------------------------------------
// fp32 -> bf16 convert, all three tensors in one launch (8 elems/thread)
// ---------------------------------------------------------------------------
__global__ __launch_bounds__(256) void cvt_all(
    const float* __restrict__ s0, unsigned short* __restrict__ d0, int n0,
    const float* __restrict__ s1, unsigned short* __restrict__ d1, int n1,
    const float* __restrict__ s2, unsigned short* __restrict__ d2, int n2) {
  int i = (blockIdx.x * 256 + threadIdx.x) * 8;
  const float* src;
  unsigned short* dst;
  if (i < n0) {
    src = s0; dst = d0;
  } else if (i < n0 + n1) {
    src = s1; dst = d1; i -= n0;
  } else {
    src = s2; dst = d2; i -= n0 + n1;
    if (i >= n2) return;
  }
  const float4 a = *(const float4*)(src + i);
  const float4 b = *(const float4*)(src + i + 4);
  ushort4 oa, ob;
  oa.x = f2bf(a.x); oa.y = f2bf(a.y); oa.z = f2bf(a.z); oa.w = f2bf(a.w);
  ob.x = f2bf(b.x); ob.y = f2bf(b.y); ob.z = f2bf(b.z); ob.w = f2bf(b.w);
  *(ushort4*)(dst + i) = oa;
  *(ushort4*)(dst + i + 4) = ob;
}

// ---------------------------------------------------------------------------
// Deep-pipelined MFMA bf16 GEMM: BM=256, BK=64, 8 waves (2Mx4N), per-wave
// 128x64 output (MODE 0, BROWS=256) or 128x32 (MODE 1, BROWS=128).
// C[m,n] = sum_k A[m,k]*W[n,k].
// LDS in fragment order ([k-chunk8][row] 16B chunks): staging is linear
// (global_load_lds-compatible) AND ds_read_b128 frag reads are contiguous
// per 16 lanes -> zero bank conflicts (verified structure, SQ_LDS_BANK_CONFLICT=0).
// Double-buffered: tile t read from buf[t&1]; tile t+1 staged into buf[t&1^1]
// during phases 0-1 of tile t; single vmcnt(0) drain per K-tile via
// __syncthreads ~2.5 phases after the youngest issue (latency hidden).
// Per K-tile: 4 quadrant phases (kk x mh), each 16(or 8) MFMA wrapped in
// setprio(1), separated by raw s_barrier (no vmcnt drain mid-tile).
// MODE 0: +bias; q,k bf16 natural [B,NH,S,HD]; v in PV-fragment-ready tiled
//   layout vt4 (same as attention kernel expects).
// MODE 1: +bias+residual fp32 out.
// ---------------------------------------------------------------------------
template <int MODE, int BROWS>
__global__ __launch_bounds__(512) void gemm256(
    const unsigned short* __restrict__ A, const unsigned short* __restrict__ W,
    const float* __restrict__ bias, const float* __restrict__ residual,
    unsigned short* __restrict__ q, unsigned short* __restrict__ k,
    unsigned short* __restrict__ v, float* __restrict__ outf) {
  constexpr int K = HIDDEN;          // 2048
  constexpr int NT = K / 64;         // 32 K-tiles
  constexpr int NB = BROWS / 64;     // N-frags per wave: 4 (qkv) / 2 (dense)
  constexpr int BTB = BROWS * 128;   // B tile bytes
  // A buffers: [0, 65536) bytes; B buffers: [65536, 65536 + 2*BTB)
  __shared__ __align__(16) unsigned short L[(65536 + 2 * BTB) / 2];

  const int tid = threadIdx.x;
  const int lane = tid & 63;
  const int l15 = lane & 15;
  const int quad = (lane >> 4) & 3;
  const int wave = tid >> 6;
  const int wr = wave >> 2;  // 0..1 -> rows wr*128
  const int wc = wave & 3;   // 0..3 -> cols wc*(BROWS/4)

  // T1: bijective XCD-aware swizzle (nwg = 384 or 256, both % 8 == 0)
  const int gx = gridDim.x;
  const int nwg = gx * gridDim.y;
  const int flat = blockIdx.y * gx + blockIdx.x;
  const int swz = (flat & 7) * (nwg >> 3) + (flat >> 3);
  const int bx = swz % gx, by = swz / gx;
  const int n0 = bx * BROWS;
  const int m0 = by << 8;

  f32x4 acc[8][NB];
#pragma unroll
  for (int i = 0; i < 8; ++i)
#pragma unroll
    for (int j = 0; j < NB; ++j) {
      f32x4 z = {0.f, 0.f, 0.f, 0.f};
      acc[i][j] = z;
    }

  // ---- staging: fragment-order chunks, linear in idx ----
  auto stageA = [&](const int t, const int buf) {
#pragma unroll
    for (int p = 0; p < 4; ++p) {
      const int idx = tid + p * 512;  // [0,2048): kg=idx>>8, row=idx&255
      gl2lds16(A + (size_t)(m0 + (idx & 255)) * K + t * 64 + (idx >> 8) * 8,
               (char*)L + buf * 32768 + idx * 16);
    }
  };
  auto stageB = [&](const int t, const int buf) {
#pragma unroll
    for (int p = 0; p < NB; ++p) {
      const int idx = tid + p * 512;  // [0, BROWS*8)
      gl2lds16(W + (size_t)(n0 + (idx & (BROWS - 1))) * K + t * 64 +
                   (idx / BROWS) * 8,
               (char*)L + 65536 + buf * BTB + idx * 16);
    }
  };

  // one K-tile: 4 quadrant phases; prefetch t+1 into buf^1 in phases 0-1
  auto ktile = [&](const int cur, const int t) {
    const char* lA = (const char*)L + cur * 32768;
    const char* lB = (const char*)L + 65536 + cur * BTB;
    const bool pf = (t + 1) < NT;
    short8 bf[NB];
#pragma unroll
    for (int kk = 0; kk < 2; ++kk) {
#pragma unroll
      for (int mh = 0; mh < 2; ++mh) {
        if (kk == 0 && mh == 0 && pf) stageA(t + 1, cur ^ 1);
        if (kk == 0 && mh == 1 && pf) stageB(t + 1, cur ^ 1);
        if (mh == 0) {
#pragma unroll
          for (int j = 0; j < NB; ++j)
            bf[j] = *(const short8*)(
                lB + (((kk * 4 + quad) * BROWS + wc * (BROWS / 4) + j * 16 +
                       l15) << 4));
        }
        short8 af[4];
#pragma unroll
        for (int i = 0; i < 4; ++i)
          af[i] = *(const short8*)(
              lA + (((kk * 4 + quad) * 256 + wr * 128 + (mh * 4 + i) * 16 +
                     l15) << 4));
        __builtin_amdgcn_s_setprio(1);
#pragma unroll
        for (int i = 0; i < 4; ++i)
#pragma unroll
          for (int j = 0; j < NB; ++j)
            acc[mh * 4 + i][j] = __builtin_amdgcn_mfma_f32_16x16x32_bf16(
                af[i], bf[j], acc[mh * 4 + i][j], 0, 0, 0);
        __builtin_amdgcn_s_setprio(0);
        if (!(kk == 1 && mh == 1)) __builtin_amdgcn_s_barrier();
      }
    }
    // drains vmcnt(0): tile t+1 fully staged; all reads of buf[cur] done
    // before next tile's prefetch overwrites it.
    __syncthreads();
  };

  stageA(0, 0);
  stageB(0, 0);
  __syncthreads();
  for (int t = 0; t < NT; t += 2) {
    ktile(0, t);
    ktile(1, t + 1);
  }

  if (MODE == 0) {
#pragma unroll
    for (int mi = 0; mi < 8; ++mi) {
#pragma unroll
      for (int nj = 0; nj < NB; ++nj) {
        const int n = n0 + wc * (BROWS / 4) + nj * 16 + l15;
        const float bi = bias[n];
        const int h = n / 384;
        const int rem = n - h * 384;
        const int which = rem >> 7;
        const int d = rem & 127;
        const int mb = m0 + wr * 128 + mi * 16 + quad * 4;  // mb % 4 == 0
        const int bb = mb >> 11, ssb = mb & 2047;
        const int bh = (bb << 4) + h;
        if (which == 2) {
          // vt4 packed store: 4 consecutive k (=s) in one ushort4
          const int dt = d >> 4, dl = d & 15;
          const int ksup = ssb >> 5, ntl = (ssb >> 4) & 1, qq = (ssb >> 2) & 3;
          ushort4 pk;
          pk.x = f2bf(acc[mi][nj][0] + bi);
          pk.y = f2bf(acc[mi][nj][1] + bi);
          pk.z = f2bf(acc[mi][nj][2] + bi);
          pk.w = f2bf(acc[mi][nj][3] + bi);
          *(ushort4*)(v +
                      ((((size_t)(bh * 8 + dt) * (SEQ / 32) + ksup) * 4 + qq) *
                       16 + dl) * 8 + ntl * 4) = pk;
        } else {
          unsigned short* dst = (which == 0) ? q : k;
#pragma unroll
          for (int p = 0; p < 4; ++p)
            dst[((size_t)(bh << 11) + ssb + p) * HD + d] =
                f2bf(acc[mi][nj][p] + bi);
        }
      }
    }
  } else {
#pragma unroll
    for (int mi = 0; mi < 8; ++mi) {
#pragma unroll
      for (int nj = 0; nj < NB; ++nj) {
        const int n = n0 + wc * (BROWS / 4) + nj * 16 + l15;
        const float bi = bias[n];
#pragma unroll
        for (int p = 0; p < 4; ++p) {
          const int m = m0 + wr * 128 + mi * 16 + quad * 4 + p;
          outf[(size_t)m * HIDDEN + n] =
              acc[mi][nj][p] + bi + residual[(size_t)m * HIDDEN + n];
        }
      }
    }
  }
}

// ---------------------------------------------------------------------------
// Hybrid MFMA flash attention (causal + alibi). (unchanged this round)
// ---------------------------------------------------------------------------
__global__ __launch_bounds__(256) void attn_mfma3(
    const unsigned short* __restrict__ qb, const unsigned short* __restrict__ kb,
    const unsigned short* __restrict__ vt4, unsigned short* __restrict__ ctx) {
  __shared__ __align__(16) unsigned short Ks[8192];  // [nt4][dt4][quad4][l15:16][8]
  __shared__ __align__(16) unsigned short Vs[8192];  // [nt8][s2:2][quad4][l15:16][8]

  const int tid = threadIdx.x;
  const int lane = tid & 63;
  const int w = tid >> 6;
  const int l15 = lane & 15;
  const int quad = lane >> 4;
  const int bt = gridDim.x - 1 - blockIdx.x;  // heavy tiles first
  const int q0 = bt << 6;
  const int h = blockIdx.y, b = blockIdx.z;
  const int bh = b * NHEAD + h;
  const float slope = exp2f(-0.5f * (float)(h + 1));
  const unsigned short* qp = qb + ((size_t)bh * SEQ + q0 + w * 16) * HD;
  const unsigned short* kp = kb + (size_t)bh * SEQ * HD;
  const unsigned short* vp = vt4 + (size_t)bh * SEQ * HD;

  // Q B-frags (persist): lane n=l15 -> q-row, k-slots d = dt*32+quad*8+j
  short8 qf[4];
#pragma unroll
  for (int dt = 0; dt < 4; ++dt)
    qf[dt] = *(const short8*)(qp + (size_t)l15 * HD + dt * 32 + quad * 8);

  f32x4 O[8];
#pragma unroll
  for (int i = 0; i < 8; ++i) {
    f32x4 z = {0.f, 0.f, 0.f, 0.f};
    O[i] = z;
  }
  float mrow = -3.0e38f, lrow = 0.f;  // per-lane state for q = q0 + w*16 + l15
  const int qg = q0 + w * 16 + l15;

  for (int kt = 0; kt <= bt; ++kt) {
    // ---- stage K tile into frag order: idx=((nt*4+dt)*4+quad)*16+l15 ----
#pragma unroll
    for (int p = 0; p < 4; ++p) {
      const int idx = tid + p * 256;
      const int reg = idx >> 6;
      const int nts = reg >> 2, dts = reg & 3;
      const int qs = (idx >> 4) & 3, ls = idx & 15;
      gl2lds16(kp + (size_t)(kt * 64 + nts * 16 + ls) * HD + dts * 32 + qs * 8,
               (char*)Ks + idx * 16);
    }
    // ---- stage V tile: flat copy of contiguous vt4 chunks (2KB per nt) ----
#pragma unroll
    for (int p = 0; p < 4; ++p) {
      const int idx = tid + p * 256;
      const int ntv = idx >> 7, off = idx & 127;
      gl2lds16(vp + ((size_t)(ntv * 64 + kt * 2)) * 512 + off * 8,
               (char*)Vs + idx * 16);
    }
    __syncthreads();  // tiles ready (barrier drains vmcnt)

    // ---- S^T = K·Q^T : A=kf (LDS), B=qf. Skip fully-masked diag subtiles ----
    f32x4 sc[4];
#pragma unroll
    for (int nt = 0; nt < 4; ++nt) {
      f32x4 z = {0.f, 0.f, 0.f, 0.f};
      sc[nt] = z;
    }
    const int ntmax = (kt == bt) ? (w + 1) : 4;
#pragma unroll
    for (int dt = 0; dt < 4; ++dt) {
#pragma unroll
      for (int nt = 0; nt < 4; ++nt) {
        if (nt < ntmax) {
          const short8 kf = *(const short8*)(
              (const char*)Ks + ((((nt * 4 + dt) * 4 + quad) * 16 + l15) << 4));
          sc[nt] = __builtin_amdgcn_mfma_f32_16x16x32_bf16(kf, qf[dt], sc[nt],
                                                           0, 0, 0);
        }
      }
    }

    // ---- scale + alibi + causal (diag tile); softmax in registers ----
    const bool diag = (kt == bt);
    float pv[4][4];
    float pm = -3.0e38f;
#pragma unroll
    for (int nt = 0; nt < 4; ++nt) {
      const int kbase = kt * 64 + nt * 16 + quad * 4;
#pragma unroll
      for (int r = 0; r < 4; ++r) {
        const int kg = kbase + r;
        float s = fmaf(sc[nt][r], SCORE_SCALE, slope * (float)kg);
        if (diag && kg > qg) s = -1.0e30f;
        pv[nt][r] = s;
        pm = fmaxf(pm, s);
      }
    }
    pm = fmaxf(pm, __shfl_xor(pm, 16, 64));
    pm = fmaxf(pm, __shfl_xor(pm, 32, 64));
    const float mnew = fmaxf(mrow, pm);
    const float alpha = __expf(mrow - mnew);
    mrow = mnew;
    float rsum = 0.f;
#pragma unroll
    for (int nt = 0; nt < 4; ++nt)
#pragma unroll
      for (int r = 0; r < 4; ++r) {
        const float p = __expf(pv[nt][r] - mnew);
        pv[nt][r] = p;
        rsum += p;
      }
    rsum += __shfl_xor(rsum, 16, 64);
    rsum += __shfl_xor(rsum, 32, 64);
    lrow = lrow * alpha + rsum;

    // alpha for O rows (q = quad*4+r): fetch from in-quad lane l15=quad*4+r
    float aO[4];
#pragma unroll
    for (int r = 0; r < 4; ++r)
      aO[r] = __shfl(alpha, (quad << 4) + (quad << 2) + r, 64);
#pragma unroll
    for (int o = 0; o < 8; ++o)
#pragma unroll
      for (int r = 0; r < 4; ++r) O[o][r] *= aO[r];

    // ---- pack P into A-frags (in-lane; relabeled k-slots) ----
    union { short8 s; unsigned int u[4]; } pf[2];
#pragma unroll
    for (int nt = 0; nt < 4; ++nt) {
      const unsigned int lo =
          (unsigned int)f2bf(pv[nt][0]) | ((unsigned int)f2bf(pv[nt][1]) << 16);
      const unsigned int hi =
          (unsigned int)f2bf(pv[nt][2]) | ((unsigned int)f2bf(pv[nt][3]) << 16);
      pf[nt >> 1].u[(nt & 1) * 2] = lo;
      pf[nt >> 1].u[(nt & 1) * 2 + 1] = hi;
    }

    // ---- PV: 16 MFMA, vf from LDS (frag order) ----
#pragma unroll
    for (int s2 = 0; s2 < 2; ++s2) {
#pragma unroll
      for (int nt = 0; nt < 8; ++nt) {
        const short8 vf = *(const short8*)(
            (const char*)Vs + nt * 2048 + s2 * 1024 + quad * 256 + l15 * 16);
        O[nt] = __builtin_amdgcn_mfma_f32_16x16x32_bf16(pf[s2].s, vf, O[nt],
                                                        0, 0, 0);
      }
    }
    __syncthreads();  // LDS reads done before next staging overwrites
  }

  // ---- epilogue: O /= l, write ctx [B,S,H] bf16 ----
  const float linv = 1.f / lrow;
  float iO[4];
#pragma unroll
  for (int r = 0; r < 4; ++r)
    iO[r] = __shfl(linv, (quad << 4) + (quad << 2) + r, 64);
#pragma unroll
  for (int nt = 0; nt < 8; ++nt)
#pragma unroll
    for (int r = 0; r < 4; ++r)
      ctx[((size_t)b * SEQ + q0 + w * 16 + quad * 4 + r) * HIDDEN + h * HD +
          nt * 16 + l15] = f2bf(O[nt][r] * iO[r]);
}

// ---------------------------------------------------------------------------
extern "C" void kernel_launch(void* const* d_in, const int* in_sizes, int n_in,
                              void* d_out, int out_size, void* d_ws,
                              size_t ws_size, hipStream_t stream) {
  const float* hs = (const float*)d_in[0];
  const float* res = (const float*)d_in[1];
  // d_in[2] attention_mask: all ones -> causal only
  const float* Wqkv = (const float*)d_in[3];
  const float* bqkv = (const float*)d_in[4];
  const float* Wd = (const float*)d_in[5];
  const float* bd = (const float*)d_in[6];
  float* out = (float*)d_out;

  const size_t per = (size_t)BATCH * NHEAD * SEQ * HD;  // 8.39M elems
  const size_t n_hs = (size_t)MROWS * HIDDEN;
  const size_t n_wq = (size_t)K3 * HIDDEN;
  const size_t n_wd = (size_t)HIDDEN * HIDDEN;

  unsigned short* ws = (unsigned short*)d_ws;
  unsigned short* qb = ws;
  unsigned short* kb = qb + per;
  unsigned short* vtb = kb + per;  // v in PV-fragment tiled layout (vt4)
  unsigned short* ctxb = vtb + per;
  unsigned short* hs_bf = ctxb + n_hs;
  unsigned short* wq_bf = hs_bf + n_hs;
  unsigned short* wd_bf = wq_bf + n_wq;

  dim3 blk(256);
  const unsigned cvt_blocks = (unsigned)((n_hs + n_wq + n_wd) / 8 / 256);
  cvt_all<<<dim3(cvt_blocks), blk, 0, stream>>>(
      hs, hs_bf, (int)n_hs, Wqkv, wq_bf, (int)n_wq, Wd, wd_bf, (int)n_wd);
  // QKV GEMM: 256x256 tiles, grid 24x16 = 384 blocks (%8==0 for swizzle)
  gemm256<0, 256><<<dim3(K3 / 256, MROWS / 256), dim3(512), 0, stream>>>(
      hs_bf, wq_bf, bqkv, nullptr, qb, kb, vtb, nullptr);
  attn_mfma3<<<dim3(SEQ / 64, NHEAD, BATCH), blk, 0, stream>>>(qb, kb, vtb,
                                                               ctxb);
  // dense GEMM: 256x128 tiles, grid 16x16 = 256 blocks (1/CU, full machine)
  gemm256<1, 128><<<dim3(HIDDEN / 128, MROWS / 256), dim3(512), 0, stream>>>(
      ctxb, wd_bf, bd, res, nullptr, nullptr, nullptr, out);
}

// Round 3
// 554.975 us; speedup vs baseline: 1.0860x; 1.0120x over previous
//
#include <hip/hip_runtime.h>
#include <math.h>

#define HIDDEN 2048
#define NHEAD 16
#define HD 128
#define SEQ 2048
#define BATCH 2
#define MROWS (BATCH * SEQ)   // 4096
#define K3 (3 * HIDDEN)       // 6144

#define SCORE_SCALE 0.08838834764831845f  // 1/sqrt(128), LAYER_NUMBER=1

using short8 = __attribute__((ext_vector_type(8))) short;
using f32x4 = __attribute__((ext_vector_type(4))) float;

__device__ __forceinline__ unsigned short f2bf(float f) {
  union { float f; unsigned int u; } v; v.f = f;
  const unsigned int u = v.u;
  return (unsigned short)((u + 0x7FFFu + ((u >> 16) & 1u)) >> 16);
}

// async 16B global -> LDS (global addr per-lane; LDS dest uniform base + lane*16)
__device__ __forceinline__ void gl2lds16(const void* g, void* l) {
#pragma clang diagnostic push
#pragma clang diagnostic ignored "-Waddress-space-conversion"
  __builtin_amdgcn_global_load_lds(
      (const __attribute__((address_space(1))) unsigned int*)g,
      (__attribute__((address_space(3))) unsigned int*)l, 16, 0, 0);
#pragma clang diagnostic pop
}

// counted vmcnt wait: orders all memory ops (stages/ds_reads) around it
template <int N>
__device__ __forceinline__ void vmwait() {
  asm volatile("s_waitcnt vmcnt(%0)" ::"n"(N) : "memory");
}

template <int V> struct IC { static constexpr int v = V; };
template <bool V> struct BC { static constexpr bool v = V; };

// ---------------------------------------------------------------------------
// fp32 -> bf16 convert, all three tensors in one launch (8 elems/thread)
// ---------------------------------------------------------------------------
__global__ __launch_bounds__(256) void cvt_all(
    const float* __restrict__ s0, unsigned short* __restrict__ d0, int n0,
    const float* __restrict__ s1, unsigned short* __restrict__ d1, int n1,
    const float* __restrict__ s2, unsigned short* __restrict__ d2, int n2) {
  int i = (blockIdx.x * 256 + threadIdx.x) * 8;
  const float* src;
  unsigned short* dst;
  if (i < n0) {
    src = s0; dst = d0;
  } else if (i < n0 + n1) {
    src = s1; dst = d1; i -= n0;
  } else {
    src = s2; dst = d2; i -= n0 + n1;
    if (i >= n2) return;
  }
  const float4 a = *(const float4*)(src + i);
  const float4 b = *(const float4*)(src + i + 4);
  ushort4 oa, ob;
  oa.x = f2bf(a.x); oa.y = f2bf(a.y); oa.z = f2bf(a.z); oa.w = f2bf(a.w);
  ob.x = f2bf(b.x); ob.y = f2bf(b.y); ob.z = f2bf(b.z); ob.w = f2bf(b.w);
  *(ushort4*)(dst + i) = oa;
  *(ushort4*)(dst + i + 4) = ob;
}

// ---------------------------------------------------------------------------
// Counted-vmcnt pipelined MFMA bf16 GEMM (T3+T4+T5+T1). BM=256, BK=64,
// 8 waves (2Mx4N), per-wave 128xBROWS/4 output. C[m,n] = sum_k A[m,k]*W[n,k].
//
// Staging is split into contiguous K-HALF units (A_k0,A_k1,B_k0,B_k1; each a
// contiguous LDS range so global_load_lds stays linear). Phases = (mh,kk)
// quadrants reading only (.,kk) units. Liveness-derived schedule per tile t:
//   P0(m0,k0): stage A_k1(t+1)   [region dead since (t-1,P3)]
//   P1(m0,k1): stage B_k1(t+1)
//   P2(m1,k0): no stage
//   P3(m1,k1): stage A_k0(t+2)+B_k0(t+2) into buf[t&1]  [dead after P2]
// Waits (counted, NEVER 0 in main loop; hand-verified queue invariant at
// tile-t entry: [A_k1(t)x2, B_k1(t)x2, A_k0(t+1)x2, B_k0(t+1)x2]):
// vmcnt(W0) at tile boundary retires A_k0/B_k0(t+1); vmcnt(W1) after P0
// retires A_k1/B_k1(t). Prefetch distance = 5 phases >= HBM latency.
// No __syncthreads in the loop (it would drain vmcnt -> the round-1 stall:
// MfmaUtil 21%, all pipes idle). Per phase: {ds_reads, stage, s_barrier,
// setprio(1) MFMA setprio(0), sched_barrier(0) [rule #18: pin MFMAs before
// the barrier], [vmwait], s_barrier} — the m201 race-screened pattern.
// B-frags cached in regs per kk (read at P0/P1, reused at P2/P3).
// ---------------------------------------------------------------------------
template <int MODE, int BROWS>
__global__ __launch_bounds__(512, 2) void gemm256(
    const unsigned short* __restrict__ A, const unsigned short* __restrict__ W,
    const float* __restrict__ bias, const float* __restrict__ residual,
    unsigned short* __restrict__ q, unsigned short* __restrict__ k,
    unsigned short* __restrict__ v, float* __restrict__ outf) {
  constexpr int K = HIDDEN;          // 2048
  constexpr int NT = K / 64;         // 32 K-tiles
  constexpr int NB = BROWS / 64;     // N-frags per wave: 4 (qkv) / 2 (dense)
  constexpr int ABUF = 32768;        // bytes per A K-tile buffer (256x64 bf16)
  constexpr int AUNIT = 16384;       // bytes per A k-half unit
  constexpr int BTB = BROWS * 128;   // bytes per B K-tile buffer
  constexpr int BUNIT = BTB / 2;     // bytes per B k-half unit
  constexpr int LA = 2;              // gl2lds16/thread per A unit
  constexpr int LB = BROWS / 128;    // gl2lds16/thread per B unit (2 or 1)
  constexpr int W0 = 2 * (LA + LB);  // tile-boundary wait (steady)
  constexpr int W1 = 2 * LA + LB;    // post-P0 wait (steady)
  constexpr int WT = LA + LB;        // boundary wait entering last tile
  __shared__ __align__(16) unsigned short L[(2 * ABUF + 2 * BTB) / 2];

  const int tid = threadIdx.x;
  const int lane = tid & 63;
  const int l15 = lane & 15;
  const int quad = (lane >> 4) & 3;
  const int wave = tid >> 6;
  const int wr = wave >> 2;  // 0..1 -> rows wr*128
  const int wc = wave & 3;   // 0..3 -> cols wc*(BROWS/4)

  // T1: bijective XCD-aware swizzle (nwg = 384 or 256, both % 8 == 0)
  const int gx = gridDim.x;
  const int nwg = gx * gridDim.y;
  const int flat = blockIdx.y * gx + blockIdx.x;
  const int swz = (flat & 7) * (nwg >> 3) + (flat >> 3);
  const int bx = swz % gx, by = swz / gx;
  const int n0 = bx * BROWS;
  const int m0 = by << 8;

  f32x4 acc[8][NB];
#pragma unroll
  for (int i = 0; i < 8; ++i)
#pragma unroll
    for (int j = 0; j < NB; ++j) {
      f32x4 z = {0.f, 0.f, 0.f, 0.f};
      acc[i][j] = z;
    }

  // ---- unit staging: contiguous LDS range [unit base, +unit size) ----
  auto stageAk = [&](const int t, const int buf, const int kk) {
#pragma unroll
    for (int p = 0; p < LA; ++p) {
      const int idx = tid + p * 512;          // [0,1024): kc=idx>>8, row=idx&255
      gl2lds16(A + (size_t)(m0 + (idx & 255)) * K + t * 64 + kk * 32 +
                   (idx >> 8) * 8,
               (char*)L + buf * ABUF + kk * AUNIT + idx * 16);
    }
  };
  auto stageBk = [&](const int t, const int buf, const int kk) {
#pragma unroll
    for (int p = 0; p < LB; ++p) {
      const int idx = tid + p * 512;          // [0,BROWS*4)
      gl2lds16(W + (size_t)(n0 + (idx & (BROWS - 1))) * K + t * 64 + kk * 32 +
                   (idx / BROWS) * 8,
               (char*)L + 2 * ABUF + buf * BTB + kk * BUNIT + idx * 16);
    }
  };

  auto tile = [&](const int c, const int t, auto s1c, auto s0c, auto wp0c,
                  auto wp3c) {
    constexpr bool S1 = decltype(s1c)::v;   // stage k1 units of t+1
    constexpr bool S0 = decltype(s0c)::v;   // stage k0 units of t+2
    constexpr int WP0 = decltype(wp0c)::v;  // wait after P0
    constexpr int WP3 = decltype(wp3c)::v;  // wait after P3 (tile boundary)
    const char* lA = (const char*)L + c * ABUF;
    const char* lB = (const char*)L + 2 * ABUF + c * BTB;
    short8 af[4], bfk0[NB], bfk1[NB];
    // ---------------- P0: (mh=0, kk=0) ----------------
#pragma unroll
    for (int j = 0; j < NB; ++j)
      bfk0[j] = *(const short8*)(
          lB + ((quad * BROWS + wc * (BROWS / 4) + j * 16 + l15) << 4));
#pragma unroll
    for (int i = 0; i < 4; ++i)
      af[i] = *(const short8*)(
          lA + ((quad * 256 + wr * 128 + i * 16 + l15) << 4));
    if (S1) stageAk(t + 1, c ^ 1, 1);
    __builtin_amdgcn_s_barrier();
    __builtin_amdgcn_s_setprio(1);
#pragma unroll
    for (int i = 0; i < 4; ++i)
#pragma unroll
      for (int j = 0; j < NB; ++j)
        acc[i][j] = __builtin_amdgcn_mfma_f32_16x16x32_bf16(af[i], bfk0[j],
                                                            acc[i][j], 0, 0, 0);
    __builtin_amdgcn_s_setprio(0);
    __builtin_amdgcn_sched_barrier(0);
    vmwait<WP0>();
    __builtin_amdgcn_s_barrier();
    // ---------------- P1: (mh=0, kk=1) ----------------
#pragma unroll
    for (int j = 0; j < NB; ++j)
      bfk1[j] = *(const short8*)(
          lB + BUNIT + ((quad * BROWS + wc * (BROWS / 4) + j * 16 + l15) << 4));
#pragma unroll
    for (int i = 0; i < 4; ++i)
      af[i] = *(const short8*)(
          lA + AUNIT + ((quad * 256 + wr * 128 + i * 16 + l15) << 4));
    if (S1) stageBk(t + 1, c ^ 1, 1);
    __builtin_amdgcn_s_barrier();
    __builtin_amdgcn_s_setprio(1);
#pragma unroll
    for (int i = 0; i < 4; ++i)
#pragma unroll
      for (int j = 0; j < NB; ++j)
        acc[i][j] = __builtin_amdgcn_mfma_f32_16x16x32_bf16(af[i], bfk1[j],
                                                            acc[i][j], 0, 0, 0);
    __builtin_amdgcn_s_setprio(0);
    __builtin_amdgcn_sched_barrier(0);
    __builtin_amdgcn_s_barrier();
    // ---------------- P2: (mh=1, kk=0) ----------------
#pragma unroll
    for (int i = 0; i < 4; ++i)
      af[i] = *(const short8*)(
          lA + ((quad * 256 + wr * 128 + 64 + i * 16 + l15) << 4));
    __builtin_amdgcn_s_barrier();
    __builtin_amdgcn_s_setprio(1);
#pragma unroll
    for (int i = 0; i < 4; ++i)
#pragma unroll
      for (int j = 0; j < NB; ++j)
        acc[4 + i][j] = __builtin_amdgcn_mfma_f32_16x16x32_bf16(
            af[i], bfk0[j], acc[4 + i][j], 0, 0, 0);
    __builtin_amdgcn_s_setprio(0);
    __builtin_amdgcn_sched_barrier(0);
    __builtin_amdgcn_s_barrier();
    // ---------------- P3: (mh=1, kk=1) ----------------
#pragma unroll
    for (int i = 0; i < 4; ++i)
      af[i] = *(const short8*)(
          lA + AUNIT + ((quad * 256 + wr * 128 + 64 + i * 16 + l15) << 4));
    if (S0) {
      stageAk(t + 2, c, 0);
      stageBk(t + 2, c, 0);
    }
    __builtin_amdgcn_s_barrier();
    __builtin_amdgcn_s_setprio(1);
#pragma unroll
    for (int i = 0; i < 4; ++i)
#pragma unroll
      for (int j = 0; j < NB; ++j)
        acc[4 + i][j] = __builtin_amdgcn_mfma_f32_16x16x32_bf16(
            af[i], bfk1[j], acc[4 + i][j], 0, 0, 0);
    __builtin_amdgcn_s_setprio(0);
    __builtin_amdgcn_sched_barrier(0);
    vmwait<WP3>();
    __builtin_amdgcn_s_barrier();
  };

  // prologue: issue order A_k0(0),B_k0(0),A_k1(0),B_k1(0),A_k0(1),B_k0(1);
  // wait W0 retires the first two (everything tile-0-P0 reads).
  stageAk(0, 0, 0);
  stageBk(0, 0, 0);
  stageAk(0, 0, 1);
  stageBk(0, 0, 1);
  stageAk(1, 1, 0);
  stageBk(1, 1, 0);
  vmwait<W0>();
  __builtin_amdgcn_s_barrier();

#pragma unroll 1
  for (int t = 0; t < NT - 2; ++t)
    tile(t & 1, t, BC<true>{}, BC<true>{}, IC<W1>{}, IC<W0>{});
  tile(NT & 1, NT - 2, BC<true>{}, BC<false>{}, IC<W1>{}, IC<WT>{});
  tile((NT - 1) & 1, NT - 1, BC<false>{}, BC<false>{}, IC<0>{}, IC<0>{});

  if (MODE == 0) {
#pragma unroll
    for (int mi = 0; mi < 8; ++mi) {
#pragma unroll
      for (int nj = 0; nj < NB; ++nj) {
        const int n = n0 + wc * (BROWS / 4) + nj * 16 + l15;
        const float bi = bias[n];
        const int h = n / 384;
        const int rem = n - h * 384;
        const int which = rem >> 7;
        const int d = rem & 127;
        const int mb = m0 + wr * 128 + mi * 16 + quad * 4;  // mb % 4 == 0
        const int bb = mb >> 11, ssb = mb & 2047;
        const int bh = (bb << 4) + h;
        if (which == 2) {
          // vt4 packed store: 4 consecutive k (=s) in one ushort4
          const int dt = d >> 4, dl = d & 15;
          const int ksup = ssb >> 5, ntl = (ssb >> 4) & 1, qq = (ssb >> 2) & 3;
          ushort4 pk;
          pk.x = f2bf(acc[mi][nj][0] + bi);
          pk.y = f2bf(acc[mi][nj][1] + bi);
          pk.z = f2bf(acc[mi][nj][2] + bi);
          pk.w = f2bf(acc[mi][nj][3] + bi);
          *(ushort4*)(v +
                      ((((size_t)(bh * 8 + dt) * (SEQ / 32) + ksup) * 4 + qq) *
                       16 + dl) * 8 + ntl * 4) = pk;
        } else {
          unsigned short* dst = (which == 0) ? q : k;
#pragma unroll
          for (int p = 0; p < 4; ++p)
            dst[((size_t)(bh << 11) + ssb + p) * HD + d] =
                f2bf(acc[mi][nj][p] + bi);
        }
      }
    }
  } else {
#pragma unroll
    for (int mi = 0; mi < 8; ++mi) {
#pragma unroll
      for (int nj = 0; nj < NB; ++nj) {
        const int n = n0 + wc * (BROWS / 4) + nj * 16 + l15;
        const float bi = bias[n];
#pragma unroll
        for (int p = 0; p < 4; ++p) {
          const int m = m0 + wr * 128 + mi * 16 + quad * 4 + p;
          outf[(size_t)m * HIDDEN + n] =
              acc[mi][nj][p] + bi + residual[(size_t)m * HIDDEN + n];
        }
      }
    }
  }
}

// ---------------------------------------------------------------------------
// Hybrid MFMA flash attention (causal + alibi). (unchanged this round)
// ---------------------------------------------------------------------------
__global__ __launch_bounds__(256) void attn_mfma3(
    const unsigned short* __restrict__ qb, const unsigned short* __restrict__ kb,
    const unsigned short* __restrict__ vt4, unsigned short* __restrict__ ctx) {
  __shared__ __align__(16) unsigned short Ks[8192];  // [nt4][dt4][quad4][l15:16][8]
  __shared__ __align__(16) unsigned short Vs[8192];  // [nt8][s2:2][quad4][l15:16][8]

  const int tid = threadIdx.x;
  const int lane = tid & 63;
  const int w = tid >> 6;
  const int l15 = lane & 15;
  const int quad = lane >> 4;
  const int bt = gridDim.x - 1 - blockIdx.x;  // heavy tiles first
  const int q0 = bt << 6;
  const int h = blockIdx.y, b = blockIdx.z;
  const int bh = b * NHEAD + h;
  const float slope = exp2f(-0.5f * (float)(h + 1));
  const unsigned short* qp = qb + ((size_t)bh * SEQ + q0 + w * 16) * HD;
  const unsigned short* kp = kb + (size_t)bh * SEQ * HD;
  const unsigned short* vp = vt4 + (size_t)bh * SEQ * HD;

  // Q B-frags (persist): lane n=l15 -> q-row, k-slots d = dt*32+quad*8+j
  short8 qf[4];
#pragma unroll
  for (int dt = 0; dt < 4; ++dt)
    qf[dt] = *(const short8*)(qp + (size_t)l15 * HD + dt * 32 + quad * 8);

  f32x4 O[8];
#pragma unroll
  for (int i = 0; i < 8; ++i) {
    f32x4 z = {0.f, 0.f, 0.f, 0.f};
    O[i] = z;
  }
  float mrow = -3.0e38f, lrow = 0.f;  // per-lane state for q = q0 + w*16 + l15
  const int qg = q0 + w * 16 + l15;

  for (int kt = 0; kt <= bt; ++kt) {
    // ---- stage K tile into frag order: idx=((nt*4+dt)*4+quad)*16+l15 ----
#pragma unroll
    for (int p = 0; p < 4; ++p) {
      const int idx = tid + p * 256;
      const int reg = idx >> 6;
      const int nts = reg >> 2, dts = reg & 3;
      const int qs = (idx >> 4) & 3, ls = idx & 15;
      gl2lds16(kp + (size_t)(kt * 64 + nts * 16 + ls) * HD + dts * 32 + qs * 8,
               (char*)Ks + idx * 16);
    }
    // ---- stage V tile: flat copy of contiguous vt4 chunks (2KB per nt) ----
#pragma unroll
    for (int p = 0; p < 4; ++p) {
      const int idx = tid + p * 256;
      const int ntv = idx >> 7, off = idx & 127;
      gl2lds16(vp + ((size_t)(ntv * 64 + kt * 2)) * 512 + off * 8,
               (char*)Vs + idx * 16);
    }
    __syncthreads();  // tiles ready (barrier drains vmcnt)

    // ---- S^T = K·Q^T : A=kf (LDS), B=qf. Skip fully-masked diag subtiles ----
    f32x4 sc[4];
#pragma unroll
    for (int nt = 0; nt < 4; ++nt) {
      f32x4 z = {0.f, 0.f, 0.f, 0.f};
      sc[nt] = z;
    }
    const int ntmax = (kt == bt) ? (w + 1) : 4;
#pragma unroll
    for (int dt = 0; dt < 4; ++dt) {
#pragma unroll
      for (int nt = 0; nt < 4; ++nt) {
        if (nt < ntmax) {
          const short8 kf = *(const short8*)(
              (const char*)Ks + ((((nt * 4 + dt) * 4 + quad) * 16 + l15) << 4));
          sc[nt] = __builtin_amdgcn_mfma_f32_16x16x32_bf16(kf, qf[dt], sc[nt],
                                                           0, 0, 0);
        }
      }
    }

    // ---- scale + alibi + causal (diag tile); softmax in registers ----
    const bool diag = (kt == bt);
    float pv[4][4];
    float pm = -3.0e38f;
#pragma unroll
    for (int nt = 0; nt < 4; ++nt) {
      const int kbase = kt * 64 + nt * 16 + quad * 4;
#pragma unroll
      for (int r = 0; r < 4; ++r) {
        const int kg = kbase + r;
        float s = fmaf(sc[nt][r], SCORE_SCALE, slope * (float)kg);
        if (diag && kg > qg) s = -1.0e30f;
        pv[nt][r] = s;
        pm = fmaxf(pm, s);
      }
    }
    pm = fmaxf(pm, __shfl_xor(pm, 16, 64));
    pm = fmaxf(pm, __shfl_xor(pm, 32, 64));
    const float mnew = fmaxf(mrow, pm);
    const float alpha = __expf(mrow - mnew);
    mrow = mnew;
    float rsum = 0.f;
#pragma unroll
    for (int nt = 0; nt < 4; ++nt)
#pragma unroll
      for (int r = 0; r < 4; ++r) {
        const float p = __expf(pv[nt][r] - mnew);
        pv[nt][r] = p;
        rsum += p;
      }
    rsum += __shfl_xor(rsum, 16, 64);
    rsum += __shfl_xor(rsum, 32, 64);
    lrow = lrow * alpha + rsum;

    // alpha for O rows (q = quad*4+r): fetch from in-quad lane l15=quad*4+r
    float aO[4];
#pragma unroll
    for (int r = 0; r < 4; ++r)
      aO[r] = __shfl(alpha, (quad << 4) + (quad << 2) + r, 64);
#pragma unroll
    for (int o = 0; o < 8; ++o)
#pragma unroll
      for (int r = 0; r < 4; ++r) O[o][r] *= aO[r];

    // ---- pack P into A-frags (in-lane; relabeled k-slots) ----
    union { short8 s; unsigned int u[4]; } pf[2];
#pragma unroll
    for (int nt = 0; nt < 4; ++nt) {
      const unsigned int lo =
          (unsigned int)f2bf(pv[nt][0]) | ((unsigned int)f2bf(pv[nt][1]) << 16);
      const unsigned int hi =
          (unsigned int)f2bf(pv[nt][2]) | ((unsigned int)f2bf(pv[nt][3]) << 16);
      pf[nt >> 1].u[(nt & 1) * 2] = lo;
      pf[nt >> 1].u[(nt & 1) * 2 + 1] = hi;
    }

    // ---- PV: 16 MFMA, vf from LDS (frag order) ----
#pragma unroll
    for (int s2 = 0; s2 < 2; ++s2) {
#pragma unroll
      for (int nt = 0; nt < 8; ++nt) {
        const short8 vf = *(const short8*)(
            (const char*)Vs + nt * 2048 + s2 * 1024 + quad * 256 + l15 * 16);
        O[nt] = __builtin_amdgcn_mfma_f32_16x16x32_bf16(pf[s2].s, vf, O[nt],
                                                        0, 0, 0);
      }
    }
    __syncthreads();  // LDS reads done before next staging overwrites
  }

  // ---- epilogue: O /= l, write ctx [B,S,H] bf16 ----
  const float linv = 1.f / lrow;
  float iO[4];
#pragma unroll
  for (int r = 0; r < 4; ++r)
    iO[r] = __shfl(linv, (quad << 4) + (quad << 2) + r, 64);
#pragma unroll
  for (int nt = 0; nt < 8; ++nt)
#pragma unroll
    for (int r = 0; r < 4; ++r)
      ctx[((size_t)b * SEQ + q0 + w * 16 + quad * 4 + r) * HIDDEN + h * HD +
          nt * 16 + l15] = f2bf(O[nt][r] * iO[r]);
}

// ---------------------------------------------------------------------------
extern "C" void kernel_launch(void* const* d_in, const int* in_sizes, int n_in,
                              void* d_out, int out_size, void* d_ws,
                              size_t ws_size, hipStream_t stream) {
  const float* hs = (const float*)d_in[0];
  const float* res = (const float*)d_in[1];
  // d_in[2] attention_mask: all ones -> causal only
  const float* Wqkv = (const float*)d_in[3];
  const float* bqkv = (const float*)d_in[4];
  const float* Wd = (const float*)d_in[5];
  const float* bd = (const float*)d_in[6];
  float* out = (float*)d_out;

  const size_t per = (size_t)BATCH * NHEAD * SEQ * HD;  // 8.39M elems
  const size_t n_hs = (size_t)MROWS * HIDDEN;
  const size_t n_wq = (size_t)K3 * HIDDEN;
  const size_t n_wd = (size_t)HIDDEN * HIDDEN;

  unsigned short* ws = (unsigned short*)d_ws;
  unsigned short* qb = ws;
  unsigned short* kb = qb + per;
  unsigned short* vtb = kb + per;  // v in PV-fragment tiled layout (vt4)
  unsigned short* ctxb = vtb + per;
  unsigned short* hs_bf = ctxb + n_hs;
  unsigned short* wq_bf = hs_bf + n_hs;
  unsigned short* wd_bf = wq_bf + n_wq;

  dim3 blk(256);
  const unsigned cvt_blocks = (unsigned)((n_hs + n_wq + n_wd) / 8 / 256);
  cvt_all<<<dim3(cvt_blocks), blk, 0, stream>>>(
      hs, hs_bf, (int)n_hs, Wqkv, wq_bf, (int)n_wq, Wd, wd_bf, (int)n_wd);
  // QKV GEMM: 256x256 tiles, grid 24x16 = 384 blocks (%8==0 for swizzle)
  gemm256<0, 256><<<dim3(K3 / 256, MROWS / 256), dim3(512), 0, stream>>>(
      hs_bf, wq_bf, bqkv, nullptr, qb, kb, vtb, nullptr);
  attn_mfma3<<<dim3(SEQ / 64, NHEAD, BATCH), blk, 0, stream>>>(qb, kb, vtb,
                                                               ctxb);
  // dense GEMM: 256x128 tiles, grid 16x16 = 256 blocks (1/CU, full machine)
  gemm256<1, 128><<<dim3(HIDDEN / 128, MROWS / 256), dim3(512), 0, stream>>>(
      ctxb, wd_bf, bd, res, nullptr, nullptr, nullptr, out);
}